// Round 7
// baseline (13185.332 us; speedup 1.0000x reference)
//
#include <hip/hip_runtime.h>
#include <hip/hip_bf16.h>
#include <cstdint>
#include <cstddef>

#define DEV __device__ __forceinline__

typedef _Float16 h2v __attribute__((ext_vector_type(2)));

DEV float sigmoidf_(float x) { return 1.0f / (1.0f + __expf(-x)); }
DEV float tanhf_(float x) {
    float e = __expf(2.0f * x);
    return 1.0f - 2.0f / (e + 1.0f);
}
DEV h2v asH2(unsigned x) { union { unsigned u; h2v h; } c; c.u = x; return c.h; }

// ---------------------------------------------------------------------------
// Pack Whh rows to f16 pairs, scan-coalesced layout:
// whhF[L][q][j][u] = half2(W_L[q*64+u][2j], W_L[q*64+u][2j+1])
// ---------------------------------------------------------------------------
__global__ __launch_bounds__(256) void pack_whh(
    const float* __restrict__ l1Whh, const float* __restrict__ l2Whh,
    unsigned* __restrict__ whhF)
{
    int idx = blockIdx.x * 256 + threadIdx.x;   // 6*4*32*64 = 49152
    int u = idx & 63;
    int j = (idx >> 6) & 31;
    int q = (idx >> 11) & 3;
    int L = idx >> 13;
    const float* W = (L < 3) ? l1Whh + (size_t)L * 16384 : l2Whh + (size_t)(L - 3) * 16384;
    const float* row = W + (size_t)(q * 64 + u) * 64;
    union { h2v h; unsigned u32; } c;
    c.h = (h2v){(_Float16)row[2 * j], (_Float16)row[2 * j + 1]};
    whhF[idx] = c.u32;
}

// ---------------------------------------------------------------------------
// Input projection: xg[b,t,u*4+q] = bias[g] + sum_i (x[b,t,i]+gate?) * Wih[g,i]
// unit-major output so scan lane u reads its 4 gate preacts as one float4.
// ---------------------------------------------------------------------------
__global__ __launch_bounds__(256) void proj_kernel(
    const float* __restrict__ x, const float* __restrict__ Wih,
    const float* __restrict__ bias, const float* __restrict__ gate,
    float* __restrict__ xg, int D, int T)
{
    __shared__ float xS[16 * 64];
    int tb = T / 16;
    int b  = blockIdx.x / tb;
    int t0 = (blockIdx.x % tb) * 16;
    int tid = threadIdx.x;

    int n = 16 * D;
    for (int e = tid; e < n; e += 256) {
        int t = e / D;
        int i = e - t * D;
        float v = x[((size_t)(b * T + t0 + t)) * D + i];
        if (gate) v += gate[b * T + t0 + t];
        xS[t * D + i] = v;
    }
    __syncthreads();

    int g = tid;
    float acc[16];
    float bg = bias[g];
#pragma unroll
    for (int t = 0; t < 16; t++) acc[t] = bg;

    const float* wr = Wih + (size_t)g * D;
    for (int i = 0; i < D; i++) {
        float w = wr[i];
#pragma unroll
        for (int t = 0; t < 16; t++) acc[t] += xS[t * D + i] * w;
    }

    float* og = xg + ((size_t)(b * T + t0)) * 256 + (g & 63) * 4 + (g >> 6);
#pragma unroll
    for (int t = 0; t < 16; t++) og[(size_t)t * 256] = acc[t];
}

// ---------------------------------------------------------------------------
// LSTM scan v7: ONE WAVE per batch element, no barriers. Lane u owns unit u:
// all 4 gate rows of Whh in 128 VGPRs as packed f16 pairs; dot via
// v_dot2_f32_f16 (f32 accumulate). h broadcast via 8 ds_read_b128/step.
// KEY FIX vs v6: each loaded weight word is pinned into a VGPR with an
// empty asm "+v" constraint -- v6's VGPR_Count=84 proved the compiler
// rematerialized the loads inside the time loop (128 global re-loads per
// step on the serial chain). The opaque asm forbids that.
// ---------------------------------------------------------------------------
__global__ __launch_bounds__(64, 1) void scan_kernel(
    const float* __restrict__ xg, const unsigned* __restrict__ whhF,
    const float* __restrict__ h0, const float* __restrict__ c0,
    float* __restrict__ Hout, int T)
{
    __shared__ __align__(16) _Float16 hbuf[64];
    int b = blockIdx.x;
    int u = threadIdx.x;

    // 4 gate rows x 32 f16-pairs, coalesced one-time load, register-pinned.
    unsigned w[128];
#pragma unroll
    for (int k = 0; k < 128; k++) {
        w[k] = whhF[(size_t)k * 64 + u];
        asm volatile("" : "+v"(w[k]));   // opaque: forbid rematerialization
    }

    float c = c0[b * 64 + u];
    float h = h0[b * 64 + u];
    hbuf[u] = (_Float16)h;

    const float4* xp = (const float4*)(xg + (size_t)b * T * 256) + u;
    float4 xb[4];
#pragma unroll
    for (int k = 0; k < 4; k++) xb[k] = xp[(size_t)k * 64];

    float* hout = Hout + (size_t)b * T * 64 + u;
    const uint4* hv4 = (const uint4*)hbuf;

    for (int t = 0; t < T; t += 4) {
#pragma unroll
        for (int k = 0; k < 4; k++) {
            int tp = t + 4 + k; if (tp > T - 1) tp = T - 1;
            float4 xn = xp[(size_t)tp * 64];   // prefetch, stays in flight

            float ai = xb[k].x, af = xb[k].y, ag = xb[k].z, ao = xb[k].w;
#pragma unroll
            for (int j = 0; j < 8; j++) {
                uint4 hp = hv4[j];             // 8 f16 of h (broadcast read)
                unsigned hh[4] = {hp.x, hp.y, hp.z, hp.w};
#pragma unroll
                for (int p = 0; p < 4; p++) {
                    h2v hx = asH2(hh[p]);
                    int pi = j * 4 + p;
                    ai = __builtin_amdgcn_fdot2(hx, asH2(w[0 * 32 + pi]), ai, false);
                    af = __builtin_amdgcn_fdot2(hx, asH2(w[1 * 32 + pi]), af, false);
                    ag = __builtin_amdgcn_fdot2(hx, asH2(w[2 * 32 + pi]), ag, false);
                    ao = __builtin_amdgcn_fdot2(hx, asH2(w[3 * 32 + pi]), ao, false);
                }
            }

            c = sigmoidf_(af) * c + sigmoidf_(ai) * tanhf_(ag);
            h = sigmoidf_(ao) * tanhf_(c);

            hbuf[u] = (_Float16)h;             // next step's broadcast source
            hout[(size_t)(t + k) * 64] = h;    // fire-and-forget global store
            xb[k] = xn;
        }
    }
}

// ---------------------------------------------------------------------------
// Hc[b, {max,mean,std(ddof=1)}, t] over hidden dim (64). One wave per (b,t).
// ---------------------------------------------------------------------------
__global__ __launch_bounds__(256) void stats_kernel(
    const float* __restrict__ H, float* __restrict__ Hc, int T)
{
    int wid = threadIdx.x >> 6, lane = threadIdx.x & 63;
    int bt = blockIdx.x * 4 + wid;
    int b = bt / T, t = bt - b * T;

    float x = H[(size_t)bt * 64 + lane];
    float mx = x, sm = x;
#pragma unroll
    for (int m = 32; m >= 1; m >>= 1) {
        mx = fmaxf(mx, __shfl_xor(mx, m));
        sm += __shfl_xor(sm, m);
    }
    float mean = sm * (1.0f / 64.0f);
    float d = x - mean;
    float ss = d * d;
#pragma unroll
    for (int m = 32; m >= 1; m >>= 1) ss += __shfl_xor(ss, m);
    float sd = sqrtf(ss * (1.0f / 63.0f));

    if (lane == 0) {
        float* o = Hc + (size_t)b * 3 * T;
        o[0 * T + t] = mx;
        o[1 * T + t] = mean;
        o[2 * T + t] = sd;
    }
}

// ---------------------------------------------------------------------------
// Middle conv/BN chain, single workgroup (1024 threads).
// ---------------------------------------------------------------------------
template <int CIN, int COUT, int MODE>
DEV void conv_bn_stage(const float* __restrict__ in, const float* __restrict__ w,
                       const float* __restrict__ bias, float* __restrict__ out,
                       float* __restrict__ gate, int T, int tid,
                       float* rs, float* rq, float* stm, float* sti)
{
    float lsum[COUT], lss[COUT];
#pragma unroll
    for (int oc = 0; oc < COUT; oc++) { lsum[oc] = 0.f; lss[oc] = 0.f; }

    for (int k = 0; k < 8; k++) {
        int p = tid + k * 1024;
        int b = p / T;
        int t = p - b * T;
        float acc[COUT];
#pragma unroll
        for (int oc = 0; oc < COUT; oc++) acc[oc] = bias[oc];
#pragma unroll
        for (int ic = 0; ic < CIN; ic++) {
            const float* row = in + ((size_t)b * CIN + ic) * T;
            float xv[11];
#pragma unroll
            for (int kk = 0; kk < 11; kk++) {
                int tt = t + kk - 5;
                xv[kk] = (tt >= 0 && tt < T) ? row[tt] : 0.f;
            }
#pragma unroll
            for (int oc = 0; oc < COUT; oc++) {
                const float* wr = w + ((size_t)oc * CIN + ic) * 11;
#pragma unroll
                for (int kk = 0; kk < 11; kk++) acc[oc] += xv[kk] * wr[kk];
            }
        }
#pragma unroll
        for (int oc = 0; oc < COUT; oc++) {
            out[((size_t)b * COUT + oc) * T + t] = acc[oc];
            lsum[oc] += acc[oc];
            lss[oc] += acc[oc] * acc[oc];
        }
    }
    __syncthreads();

    int lane = tid & 63, wid = tid >> 6;
#pragma unroll
    for (int oc = 0; oc < COUT; oc++) {
        float s = lsum[oc], qq = lss[oc];
#pragma unroll
        for (int m = 32; m >= 1; m >>= 1) {
            s += __shfl_xor(s, m);
            qq += __shfl_xor(qq, m);
        }
        if (lane == 0) { rs[wid] = s; rq[wid] = qq; }
        __syncthreads();
        if (tid == 0) {
            float S = 0.f, Q = 0.f;
            for (int i = 0; i < 16; i++) { S += rs[i]; Q += rq[i]; }
            float m_ = S / (float)(2 * T);
            float v = Q / (float)(2 * T) - m_ * m_;
            stm[oc] = m_;
            sti[oc] = rsqrtf(v + 1e-5f);
        }
        __syncthreads();
    }

    for (int k = 0; k < 8; k++) {
        int p = tid + k * 1024;
        int b = p / T;
        int t = p - b * T;
#pragma unroll
        for (int oc = 0; oc < COUT; oc++) {
            size_t idx = ((size_t)b * COUT + oc) * T + t;
            float v = (out[idx] - stm[oc]) * sti[oc];
            if (MODE == 0) out[idx] = fmaxf(v, 0.f);
            else           gate[p] = sigmoidf_(v);
        }
    }
    __syncthreads();
}

__global__ __launch_bounds__(1024) void middle_kernel(
    const float* __restrict__ Hc,
    const float* __restrict__ w1, const float* __restrict__ b1,
    const float* __restrict__ w2, const float* __restrict__ b2,
    const float* __restrict__ w3, const float* __restrict__ b3,
    const float* __restrict__ w4, const float* __restrict__ b4,
    float* __restrict__ bufA, float* __restrict__ bufB,
    float* __restrict__ gate, int T)
{
    __shared__ float rs[16], rq[16], stm[8], sti[8];
    int tid = threadIdx.x;
    conv_bn_stage<3, 3, 0>(Hc,   w1, b1, bufA, nullptr, T, tid, rs, rq, stm, sti);
    conv_bn_stage<3, 5, 0>(bufA, w2, b2, bufB, nullptr, T, tid, rs, rq, stm, sti);
    conv_bn_stage<5, 5, 0>(bufB, w3, b3, bufA, nullptr, T, tid, rs, rq, stm, sti);
    conv_bn_stage<5, 1, 1>(bufA, w4, b4, bufB, gate,    T, tid, rs, rq, stm, sti);
}

// ---------------------------------------------------------------------------
// Head: y = sigmoid(fc2(fc1(out2))). One wave per (b,t).
// ---------------------------------------------------------------------------
__global__ __launch_bounds__(256) void final_kernel(
    const float* __restrict__ out2, const float* __restrict__ fc1w,
    const float* __restrict__ fc1b, const float* __restrict__ fc2w,
    const float* __restrict__ fc2b, float* __restrict__ out, int T)
{
    int wid = threadIdx.x >> 6, lane = threadIdx.x & 63;
    int bt = blockIdx.x * 4 + wid;

    const float* o2 = out2 + (size_t)bt * 64;
    float acc = fc1b[lane];
    const float* wr = fc1w + (size_t)lane * 64;
#pragma unroll
    for (int k = 0; k < 64; k++) acc += o2[k] * wr[k];

    float p = acc * fc2w[lane];
#pragma unroll
    for (int m = 32; m >= 1; m >>= 1) p += __shfl_xor(p, m);

    if (lane == 0) out[bt] = sigmoidf_(p + fc2b[0]);
}

// ---------------------------------------------------------------------------
extern "C" void kernel_launch(void* const* d_in, const int* in_sizes, int n_in,
                              void* d_out, int out_size, void* d_ws, size_t ws_size,
                              hipStream_t stream)
{
    const float* data  = (const float*)d_in[0];
    const float* h01   = (const float*)d_in[1];
    const float* c01   = (const float*)d_in[2];
    const float* h02   = (const float*)d_in[3];
    const float* c02   = (const float*)d_in[4];
    const float* Wih0  = (const float*)d_in[5];
    const float* Wih12 = (const float*)d_in[6];
    const float* l1Whh = (const float*)d_in[7];
    const float* l1b   = (const float*)d_in[8];
    const float* l2Wih = (const float*)d_in[9];
    const float* l2Whh = (const float*)d_in[10];
    const float* l2b   = (const float*)d_in[11];
    const float* cw1 = (const float*)d_in[12]; const float* cb1 = (const float*)d_in[13];
    const float* cw2 = (const float*)d_in[14]; const float* cb2 = (const float*)d_in[15];
    const float* cw3 = (const float*)d_in[16]; const float* cb3 = (const float*)d_in[17];
    const float* cw4 = (const float*)d_in[18]; const float* cb4 = (const float*)d_in[19];
    const float* fc1w = (const float*)d_in[20]; const float* fc1b = (const float*)d_in[21];
    const float* fc2w = (const float*)d_in[22]; const float* fc2b = (const float*)d_in[23];
    float* out = (float*)d_out;

    const int T = in_sizes[0] / (2 * 40);   // 4096
    const int B = 2;

    float* ws   = (float*)d_ws;
    float* xg   = ws;                                // B*T*256
    float* seqA = xg   + (size_t)B * T * 256;        // B*T*64
    float* seqB = seqA + (size_t)B * T * 64;         // B*T*64
    float* Hc   = seqB + (size_t)B * T * 64;         // B*3*T
    float* bufA = Hc   + (size_t)B * 3 * T;          // B*5*T
    float* bufB = bufA + (size_t)B * 5 * T;          // B*5*T
    float* gate = bufB + (size_t)B * 5 * T;          // B*T
    unsigned* whhF = (unsigned*)(gate + (size_t)B * T);  // 6*4*32*64 u32

    const int GH = 256 * 64;    // layer stride in Whh/Wih (f32 elements)
    const int FH = 4 * 32 * 64; // layer stride in whhF (u32 elements)
    dim3 pg(B * (T / 16)), pb(256);

    pack_whh<<<192, 256, 0, stream>>>(l1Whh, l2Whh, whhF);

    // ---- LSTM1 (3 layers) ----
    proj_kernel<<<pg, pb, 0, stream>>>(data, Wih0, l1b, nullptr, xg, 40, T);
    scan_kernel<<<2, 64, 0, stream>>>(xg, whhF, h01, c01, seqA, T);
    proj_kernel<<<pg, pb, 0, stream>>>(seqA, Wih12, l1b + 256, nullptr, xg, 64, T);
    scan_kernel<<<2, 64, 0, stream>>>(xg, whhF + FH, h01 + 128, c01 + 128, seqB, T);
    proj_kernel<<<pg, pb, 0, stream>>>(seqB, Wih12 + GH, l1b + 512, nullptr, xg, 64, T);
    scan_kernel<<<2, 64, 0, stream>>>(xg, whhF + 2 * FH, h01 + 256, c01 + 256, seqA, T);

    // ---- temporal-attention gate ----
    stats_kernel<<<(2 * T) / 4, 256, 0, stream>>>(seqA, Hc, T);
    middle_kernel<<<1, 1024, 0, stream>>>(Hc, cw1, cb1, cw2, cb2, cw3, cb3, cw4, cb4,
                                          bufA, bufB, gate, T);

    // ---- LSTM2 (3 layers); gate folded into first projection ----
    proj_kernel<<<pg, pb, 0, stream>>>(seqA, l2Wih, l2b, gate, xg, 64, T);
    scan_kernel<<<2, 64, 0, stream>>>(xg, whhF + 3 * FH, h02, c02, seqB, T);
    proj_kernel<<<pg, pb, 0, stream>>>(seqB, l2Wih + GH, l2b + 256, nullptr, xg, 64, T);
    scan_kernel<<<2, 64, 0, stream>>>(xg, whhF + 4 * FH, h02 + 128, c02 + 128, seqA, T);
    proj_kernel<<<pg, pb, 0, stream>>>(seqA, l2Wih + 2 * GH, l2b + 512, nullptr, xg, 64, T);
    scan_kernel<<<2, 64, 0, stream>>>(xg, whhF + 5 * FH, h02 + 256, c02 + 256, seqB, T);

    // ---- head ----
    final_kernel<<<(2 * T) / 4, 256, 0, stream>>>(seqB, fc1w, fc1b, fc2w, fc2b, out, T);
}

// Round 8
// 11500.029 us; speedup vs baseline: 1.1465x; 1.1465x over previous
//
#include <hip/hip_runtime.h>
#include <hip/hip_bf16.h>
#include <cstdint>
#include <cstddef>

#define DEV __device__ __forceinline__

typedef _Float16 h2v __attribute__((ext_vector_type(2)));
typedef unsigned u4v __attribute__((ext_vector_type(4)));

DEV float sigmoidf_(float x) { return 1.0f / (1.0f + __expf(-x)); }
DEV float tanhf_(float x) {
    float e = __expf(2.0f * x);
    return 1.0f - 2.0f / (e + 1.0f);
}
DEV h2v asH2(unsigned x) { union { unsigned u; h2v h; } c; c.u = x; return c.h; }

// ---------------------------------------------------------------------------
// Pack Whh to f16 pairs, layout chosen so scan lane u loads each weight
// quad as ONE coalesced dwordx4:
//   whhF[L][k>>2][u][k&3] = half2(W_L[row][2j], W_L[row][2j+1])
// where k = q*32+j (q = gate, j = f16-pair within row), row = q*64+u.
// ---------------------------------------------------------------------------
__global__ __launch_bounds__(256) void pack_whh(
    const float* __restrict__ l1Whh, const float* __restrict__ l2Whh,
    unsigned* __restrict__ whhF)
{
    int idx = blockIdx.x * 256 + threadIdx.x;   // 6*128*64 = 49152
    int L = idx >> 13;
    int rem = idx & 8191;
    int k = rem >> 6;          // 0..127
    int u = rem & 63;
    int q = k >> 5, j = k & 31;
    const float* W = (L < 3) ? l1Whh + (size_t)L * 16384 : l2Whh + (size_t)(L - 3) * 16384;
    const float* row = W + (size_t)(q * 64 + u) * 64;
    union { h2v h; unsigned u32; } c;
    c.h = (h2v){(_Float16)row[2 * j], (_Float16)row[2 * j + 1]};
    whhF[(size_t)L * 8192 + (size_t)(k >> 2) * 256 + u * 4 + (k & 3)] = c.u32;
}

// ---------------------------------------------------------------------------
// Input projection: xg[b,t,u*4+q] = bias[g] + sum_i (x[b,t,i]+gate?) * Wih[g,i]
// unit-major output so scan lane u reads its 4 gate preacts as one float4.
// ---------------------------------------------------------------------------
__global__ __launch_bounds__(256) void proj_kernel(
    const float* __restrict__ x, const float* __restrict__ Wih,
    const float* __restrict__ bias, const float* __restrict__ gate,
    float* __restrict__ xg, int D, int T)
{
    __shared__ float xS[16 * 64];
    int tb = T / 16;
    int b  = blockIdx.x / tb;
    int t0 = (blockIdx.x % tb) * 16;
    int tid = threadIdx.x;

    int n = 16 * D;
    for (int e = tid; e < n; e += 256) {
        int t = e / D;
        int i = e - t * D;
        float v = x[((size_t)(b * T + t0 + t)) * D + i];
        if (gate) v += gate[b * T + t0 + t];
        xS[t * D + i] = v;
    }
    __syncthreads();

    int g = tid;
    float acc[16];
    float bg = bias[g];
#pragma unroll
    for (int t = 0; t < 16; t++) acc[t] = bg;

    const float* wr = Wih + (size_t)g * D;
    for (int i = 0; i < D; i++) {
        float w = wr[i];
#pragma unroll
        for (int t = 0; t < 16; t++) acc[t] += xS[t * D + i] * w;
    }

    float* og = xg + ((size_t)(b * T + t0)) * 256 + (g & 63) * 4 + (g >> 6);
#pragma unroll
    for (int t = 0; t < 16; t++) og[(size_t)t * 256] = acc[t];
}

// ---------------------------------------------------------------------------
// LSTM scan v8: ONE WAVE per batch element, no barriers. Lane u owns unit u.
// KEY FIX vs v6/v7: weights are 32 individually-NAMED ext-vector SSA values
// (no C array -> no SROA failure -> register-resident), each loaded as one
// coalesced dwordx4, pinned with "+v" asm, kernel at waves_per_eu(1,1) for
// the 512-VGPR budget. Every prior round (VGPR_Count 48-84 vs 64-128 wanted)
// had the weight array in scratch/re-fetched per step -- the ~1250 cyc/step
// floor. Dot via v_dot2_f32_f16; h broadcast via 8 ds_read_b128/step.
// ---------------------------------------------------------------------------
__global__ __launch_bounds__(64)
__attribute__((amdgpu_waves_per_eu(1, 1)))
void scan_kernel(
    const float* __restrict__ xg, const unsigned* __restrict__ whhF,
    const float* __restrict__ h0, const float* __restrict__ c0,
    float* __restrict__ Hout, int T)
{
    __shared__ __align__(16) _Float16 hbuf[64];
    int b = blockIdx.x;
    int u = threadIdx.x;

    // 32 named weight quads (i: A0..A7, f: B0..B7, g: C0..C7, o: D0..D7)
    const u4v* wp = (const u4v*)whhF + u;   // quad j4 at wp[j4*64]
    u4v wA0 = wp[0 * 64],  wA1 = wp[1 * 64],  wA2 = wp[2 * 64],  wA3 = wp[3 * 64];
    u4v wA4 = wp[4 * 64],  wA5 = wp[5 * 64],  wA6 = wp[6 * 64],  wA7 = wp[7 * 64];
    u4v wB0 = wp[8 * 64],  wB1 = wp[9 * 64],  wB2 = wp[10 * 64], wB3 = wp[11 * 64];
    u4v wB4 = wp[12 * 64], wB5 = wp[13 * 64], wB6 = wp[14 * 64], wB7 = wp[15 * 64];
    u4v wC0 = wp[16 * 64], wC1 = wp[17 * 64], wC2 = wp[18 * 64], wC3 = wp[19 * 64];
    u4v wC4 = wp[20 * 64], wC5 = wp[21 * 64], wC6 = wp[22 * 64], wC7 = wp[23 * 64];
    u4v wD0 = wp[24 * 64], wD1 = wp[25 * 64], wD2 = wp[26 * 64], wD3 = wp[27 * 64];
    u4v wD4 = wp[28 * 64], wD5 = wp[29 * 64], wD6 = wp[30 * 64], wD7 = wp[31 * 64];

    // pin: opaque to the optimizer -> cannot be rematerialized from memory
    asm volatile("" : "+v"(wA0), "+v"(wA1), "+v"(wA2), "+v"(wA3),
                      "+v"(wA4), "+v"(wA5), "+v"(wA6), "+v"(wA7));
    asm volatile("" : "+v"(wB0), "+v"(wB1), "+v"(wB2), "+v"(wB3),
                      "+v"(wB4), "+v"(wB5), "+v"(wB6), "+v"(wB7));
    asm volatile("" : "+v"(wC0), "+v"(wC1), "+v"(wC2), "+v"(wC3),
                      "+v"(wC4), "+v"(wC5), "+v"(wC6), "+v"(wC7));
    asm volatile("" : "+v"(wD0), "+v"(wD1), "+v"(wD2), "+v"(wD3),
                      "+v"(wD4), "+v"(wD5), "+v"(wD6), "+v"(wD7));

    float c = c0[b * 64 + u];
    float h = h0[b * 64 + u];
    hbuf[u] = (_Float16)h;

    const float4* xp = (const float4*)(xg + (size_t)b * T * 256) + u;
    float4 xb[4];
#pragma unroll
    for (int k = 0; k < 4; k++) xb[k] = xp[(size_t)k * 64];

    float* hout = Hout + (size_t)b * T * 64 + u;
    const u4v* hv4 = (const u4v*)hbuf;

#define FD(HP, WV, ACC) ACC = __builtin_amdgcn_fdot2(asH2(HP), asH2(WV), ACC, false)
#define STEP4(J, WI, WF, WG, WO) { u4v hp = hv4[J];                       \
    FD(hp.x, WI.x, ai); FD(hp.y, WI.y, ai); FD(hp.z, WI.z, ai); FD(hp.w, WI.w, ai); \
    FD(hp.x, WF.x, af); FD(hp.y, WF.y, af); FD(hp.z, WF.z, af); FD(hp.w, WF.w, af); \
    FD(hp.x, WG.x, ag); FD(hp.y, WG.y, ag); FD(hp.z, WG.z, ag); FD(hp.w, WG.w, ag); \
    FD(hp.x, WO.x, ao); FD(hp.y, WO.y, ao); FD(hp.z, WO.z, ao); FD(hp.w, WO.w, ao); }

    for (int t = 0; t < T; t += 4) {
#pragma unroll
        for (int k = 0; k < 4; k++) {
            int tp = t + 4 + k; if (tp > T - 1) tp = T - 1;
            float4 xn = xp[(size_t)tp * 64];   // prefetch, stays in flight

            float ai = xb[k].x, af = xb[k].y, ag = xb[k].z, ao = xb[k].w;
            STEP4(0, wA0, wB0, wC0, wD0)
            STEP4(1, wA1, wB1, wC1, wD1)
            STEP4(2, wA2, wB2, wC2, wD2)
            STEP4(3, wA3, wB3, wC3, wD3)
            STEP4(4, wA4, wB4, wC4, wD4)
            STEP4(5, wA5, wB5, wC5, wD5)
            STEP4(6, wA6, wB6, wC6, wD6)
            STEP4(7, wA7, wB7, wC7, wD7)

            c = sigmoidf_(af) * c + sigmoidf_(ai) * tanhf_(ag);
            h = sigmoidf_(ao) * tanhf_(c);

            hbuf[u] = (_Float16)h;             // next step's broadcast source
            hout[(size_t)(t + k) * 64] = h;    // fire-and-forget global store
            xb[k] = xn;
        }
    }
#undef FD
#undef STEP4
}

// ---------------------------------------------------------------------------
// Hc[b, {max,mean,std(ddof=1)}, t] over hidden dim (64). One wave per (b,t).
// ---------------------------------------------------------------------------
__global__ __launch_bounds__(256) void stats_kernel(
    const float* __restrict__ H, float* __restrict__ Hc, int T)
{
    int wid = threadIdx.x >> 6, lane = threadIdx.x & 63;
    int bt = blockIdx.x * 4 + wid;
    int b = bt / T, t = bt - b * T;

    float x = H[(size_t)bt * 64 + lane];
    float mx = x, sm = x;
#pragma unroll
    for (int m = 32; m >= 1; m >>= 1) {
        mx = fmaxf(mx, __shfl_xor(mx, m));
        sm += __shfl_xor(sm, m);
    }
    float mean = sm * (1.0f / 64.0f);
    float d = x - mean;
    float ss = d * d;
#pragma unroll
    for (int m = 32; m >= 1; m >>= 1) ss += __shfl_xor(ss, m);
    float sd = sqrtf(ss * (1.0f / 63.0f));

    if (lane == 0) {
        float* o = Hc + (size_t)b * 3 * T;
        o[0 * T + t] = mx;
        o[1 * T + t] = mean;
        o[2 * T + t] = sd;
    }
}

// ---------------------------------------------------------------------------
// Middle conv/BN chain, single workgroup (1024 threads).
// ---------------------------------------------------------------------------
template <int CIN, int COUT, int MODE>
DEV void conv_bn_stage(const float* __restrict__ in, const float* __restrict__ w,
                       const float* __restrict__ bias, float* __restrict__ out,
                       float* __restrict__ gate, int T, int tid,
                       float* rs, float* rq, float* stm, float* sti)
{
    float lsum[COUT], lss[COUT];
#pragma unroll
    for (int oc = 0; oc < COUT; oc++) { lsum[oc] = 0.f; lss[oc] = 0.f; }

    for (int k = 0; k < 8; k++) {
        int p = tid + k * 1024;
        int b = p / T;
        int t = p - b * T;
        float acc[COUT];
#pragma unroll
        for (int oc = 0; oc < COUT; oc++) acc[oc] = bias[oc];
#pragma unroll
        for (int ic = 0; ic < CIN; ic++) {
            const float* row = in + ((size_t)b * CIN + ic) * T;
            float xv[11];
#pragma unroll
            for (int kk = 0; kk < 11; kk++) {
                int tt = t + kk - 5;
                xv[kk] = (tt >= 0 && tt < T) ? row[tt] : 0.f;
            }
#pragma unroll
            for (int oc = 0; oc < COUT; oc++) {
                const float* wr = w + ((size_t)oc * CIN + ic) * 11;
#pragma unroll
                for (int kk = 0; kk < 11; kk++) acc[oc] += xv[kk] * wr[kk];
            }
        }
#pragma unroll
        for (int oc = 0; oc < COUT; oc++) {
            out[((size_t)b * COUT + oc) * T + t] = acc[oc];
            lsum[oc] += acc[oc];
            lss[oc] += acc[oc] * acc[oc];
        }
    }
    __syncthreads();

    int lane = tid & 63, wid = tid >> 6;
#pragma unroll
    for (int oc = 0; oc < COUT; oc++) {
        float s = lsum[oc], qq = lss[oc];
#pragma unroll
        for (int m = 32; m >= 1; m >>= 1) {
            s += __shfl_xor(s, m);
            qq += __shfl_xor(qq, m);
        }
        if (lane == 0) { rs[wid] = s; rq[wid] = qq; }
        __syncthreads();
        if (tid == 0) {
            float S = 0.f, Q = 0.f;
            for (int i = 0; i < 16; i++) { S += rs[i]; Q += rq[i]; }
            float m_ = S / (float)(2 * T);
            float v = Q / (float)(2 * T) - m_ * m_;
            stm[oc] = m_;
            sti[oc] = rsqrtf(v + 1e-5f);
        }
        __syncthreads();
    }

    for (int k = 0; k < 8; k++) {
        int p = tid + k * 1024;
        int b = p / T;
        int t = p - b * T;
#pragma unroll
        for (int oc = 0; oc < COUT; oc++) {
            size_t idx = ((size_t)b * COUT + oc) * T + t;
            float v = (out[idx] - stm[oc]) * sti[oc];
            if (MODE == 0) out[idx] = fmaxf(v, 0.f);
            else           gate[p] = sigmoidf_(v);
        }
    }
    __syncthreads();
}

__global__ __launch_bounds__(1024) void middle_kernel(
    const float* __restrict__ Hc,
    const float* __restrict__ w1, const float* __restrict__ b1,
    const float* __restrict__ w2, const float* __restrict__ b2,
    const float* __restrict__ w3, const float* __restrict__ b3,
    const float* __restrict__ w4, const float* __restrict__ b4,
    float* __restrict__ bufA, float* __restrict__ bufB,
    float* __restrict__ gate, int T)
{
    __shared__ float rs[16], rq[16], stm[8], sti[8];
    int tid = threadIdx.x;
    conv_bn_stage<3, 3, 0>(Hc,   w1, b1, bufA, nullptr, T, tid, rs, rq, stm, sti);
    conv_bn_stage<3, 5, 0>(bufA, w2, b2, bufB, nullptr, T, tid, rs, rq, stm, sti);
    conv_bn_stage<5, 5, 0>(bufB, w3, b3, bufA, nullptr, T, tid, rs, rq, stm, sti);
    conv_bn_stage<5, 1, 1>(bufA, w4, b4, bufB, gate,    T, tid, rs, rq, stm, sti);
}

// ---------------------------------------------------------------------------
// Head: y = sigmoid(fc2(fc1(out2))). One wave per (b,t).
// ---------------------------------------------------------------------------
__global__ __launch_bounds__(256) void final_kernel(
    const float* __restrict__ out2, const float* __restrict__ fc1w,
    const float* __restrict__ fc1b, const float* __restrict__ fc2w,
    const float* __restrict__ fc2b, float* __restrict__ out, int T)
{
    int wid = threadIdx.x >> 6, lane = threadIdx.x & 63;
    int bt = blockIdx.x * 4 + wid;

    const float* o2 = out2 + (size_t)bt * 64;
    float acc = fc1b[lane];
    const float* wr = fc1w + (size_t)lane * 64;
#pragma unroll
    for (int k = 0; k < 64; k++) acc += o2[k] * wr[k];

    float p = acc * fc2w[lane];
#pragma unroll
    for (int m = 32; m >= 1; m >>= 1) p += __shfl_xor(p, m);

    if (lane == 0) out[bt] = sigmoidf_(p + fc2b[0]);
}

// ---------------------------------------------------------------------------
extern "C" void kernel_launch(void* const* d_in, const int* in_sizes, int n_in,
                              void* d_out, int out_size, void* d_ws, size_t ws_size,
                              hipStream_t stream)
{
    const float* data  = (const float*)d_in[0];
    const float* h01   = (const float*)d_in[1];
    const float* c01   = (const float*)d_in[2];
    const float* h02   = (const float*)d_in[3];
    const float* c02   = (const float*)d_in[4];
    const float* Wih0  = (const float*)d_in[5];
    const float* Wih12 = (const float*)d_in[6];
    const float* l1Whh = (const float*)d_in[7];
    const float* l1b   = (const float*)d_in[8];
    const float* l2Wih = (const float*)d_in[9];
    const float* l2Whh = (const float*)d_in[10];
    const float* l2b   = (const float*)d_in[11];
    const float* cw1 = (const float*)d_in[12]; const float* cb1 = (const float*)d_in[13];
    const float* cw2 = (const float*)d_in[14]; const float* cb2 = (const float*)d_in[15];
    const float* cw3 = (const float*)d_in[16]; const float* cb3 = (const float*)d_in[17];
    const float* cw4 = (const float*)d_in[18]; const float* cb4 = (const float*)d_in[19];
    const float* fc1w = (const float*)d_in[20]; const float* fc1b = (const float*)d_in[21];
    const float* fc2w = (const float*)d_in[22]; const float* fc2b = (const float*)d_in[23];
    float* out = (float*)d_out;

    const int T = in_sizes[0] / (2 * 40);   // 4096
    const int B = 2;

    float* ws   = (float*)d_ws;
    float* xg   = ws;                                // B*T*256
    float* seqA = xg   + (size_t)B * T * 256;        // B*T*64
    float* seqB = seqA + (size_t)B * T * 64;         // B*T*64
    float* Hc   = seqB + (size_t)B * T * 64;         // B*3*T
    float* bufA = Hc   + (size_t)B * 3 * T;          // B*5*T
    float* bufB = bufA + (size_t)B * 5 * T;          // B*5*T
    float* gate = bufB + (size_t)B * 5 * T;          // B*T
    unsigned* whhF = (unsigned*)(gate + (size_t)B * T);  // 6*8192 u32

    const int GH = 256 * 64;   // layer stride in Whh/Wih (f32 elements)
    const int FH = 8192;       // layer stride in whhF (u32 elements)
    dim3 pg(B * (T / 16)), pb(256);

    pack_whh<<<192, 256, 0, stream>>>(l1Whh, l2Whh, whhF);

    // ---- LSTM1 (3 layers) ----
    proj_kernel<<<pg, pb, 0, stream>>>(data, Wih0, l1b, nullptr, xg, 40, T);
    scan_kernel<<<2, 64, 0, stream>>>(xg, whhF, h01, c01, seqA, T);
    proj_kernel<<<pg, pb, 0, stream>>>(seqA, Wih12, l1b + 256, nullptr, xg, 64, T);
    scan_kernel<<<2, 64, 0, stream>>>(xg, whhF + FH, h01 + 128, c01 + 128, seqB, T);
    proj_kernel<<<pg, pb, 0, stream>>>(seqB, Wih12 + GH, l1b + 512, nullptr, xg, 64, T);
    scan_kernel<<<2, 64, 0, stream>>>(xg, whhF + 2 * FH, h01 + 256, c01 + 256, seqA, T);

    // ---- temporal-attention gate ----
    stats_kernel<<<(2 * T) / 4, 256, 0, stream>>>(seqA, Hc, T);
    middle_kernel<<<1, 1024, 0, stream>>>(Hc, cw1, cb1, cw2, cb2, cw3, cb3, cw4, cb4,
                                          bufA, bufB, gate, T);

    // ---- LSTM2 (3 layers); gate folded into first projection ----
    proj_kernel<<<pg, pb, 0, stream>>>(seqA, l2Wih, l2b, gate, xg, 64, T);
    scan_kernel<<<2, 64, 0, stream>>>(xg, whhF + 3 * FH, h02, c02, seqB, T);
    proj_kernel<<<pg, pb, 0, stream>>>(seqB, l2Wih + GH, l2b + 256, nullptr, xg, 64, T);
    scan_kernel<<<2, 64, 0, stream>>>(xg, whhF + 4 * FH, h02 + 128, c02 + 128, seqA, T);
    proj_kernel<<<pg, pb, 0, stream>>>(seqA, l2Wih + 2 * GH, l2b + 512, nullptr, xg, 64, T);
    scan_kernel<<<2, 64, 0, stream>>>(xg, whhF + 5 * FH, h02 + 256, c02 + 256, seqB, T);

    // ---- head ----
    final_kernel<<<(2 * T) / 4, 256, 0, stream>>>(seqB, fc1w, fc1b, fc2w, fc2b, out, T);
}